// Round 3
// baseline (281.602 us; speedup 1.0000x reference)
//
#include <hip/hip_runtime.h>
#include <math.h>

// B=16, C_in=32, C_out=32, H=256, W=256, K=16.
// S[b,i,v]   = (1/256) sum_w e^{-2pi i v w/256} * sum_h g[h] x[b,i,h,w],  g[h]=sum_{u<16} e^{-2pi i u h/256}
// blk[b,o,u,v] = sum_i S[b,i,u] * (Wr+iWi)[i,o,u,v]
// G[y,v]     = sum_u blk[u,v] e^{+2pi i u y/256}
// out[b,o,y,x] = (1/256)Re G[y,0] + (1/128) sum_{v=1..15} Re(G[y,v]) cos(2pi v x/256) - Im(G[y,v]) sin(2pi v x/256)

#define TWO_PI_OVER_256 0.02454369260617026f /* 2*pi/256 */

// ---------------- K1: partial S over 64-row chunks ----------------
// grid = 512 (b*32+i) x 4 chunks = 2048 blocks.
// s_part layout: [bi][chunk][32] floats: [0..15]=Re S_partial, [16..31]=Im.
__global__ __launch_bounds__(256) void k1_partial(
    const float* __restrict__ x, float* __restrict__ s_part)
{
    __shared__ float twc[256], tws[256];
    __shared__ float gre[64], gim[64];
    __shared__ float Pre[4][256], Pim[4][256];
    __shared__ float red_re[16][16], red_im[16][16];

    const int t = threadIdx.x;
    const int blk = blockIdx.x;
    const int bi = blk >> 2, chunk = blk & 3;
    const int y0 = chunk << 6;

    {
        float sv, cv;
        sincosf(TWO_PI_OVER_256 * (float)t, &sv, &cv);
        twc[t] = cv; tws[t] = sv;
    }
    __syncthreads();
    if (t < 64) {
        const int h = y0 + t;
        float gr = 0.f, gi = 0.f;
        #pragma unroll
        for (int u = 0; u < 16; ++u) {
            const int idx = (u * h) & 255;
            gr += twc[idx];
            gi -= tws[idx];
        }
        gre[t] = gr; gim[t] = gi;
    }
    __syncthreads();

    // Phase 1: partial P[w] = sum over 64 rows of g[h]*x[h,w]
    const float* img = x + (size_t)bi * 65536 + (size_t)y0 * 256;
    const int cg = t & 63, rg = t >> 6;
    float4 pr = {0.f,0.f,0.f,0.f}, pi = {0.f,0.f,0.f,0.f};
    #pragma unroll 4
    for (int k = 0; k < 16; ++k) {
        const int hl = rg + (k << 2);
        const float4 xv = *(const float4*)(img + (hl << 8) + (cg << 2));
        const float gr = gre[hl], gi = gim[hl];
        pr.x += gr * xv.x; pr.y += gr * xv.y; pr.z += gr * xv.z; pr.w += gr * xv.w;
        pi.x += gi * xv.x; pi.y += gi * xv.y; pi.z += gi * xv.z; pi.w += gi * xv.w;
    }
    *(float4*)&Pre[rg][cg << 2] = pr;
    *(float4*)&Pim[rg][cg << 2] = pi;
    __syncthreads();

    // Phase 2: S_partial[v] = (1/256) sum_w P[w] e^{-2pi i v w/256}
    {
        const int v = t >> 4, j = t & 15;
        float ar = 0.f, ai = 0.f;
        #pragma unroll
        for (int m = 0; m < 16; ++m) {
            const int w = j + (m << 4);
            const float prr = Pre[0][w] + Pre[1][w] + Pre[2][w] + Pre[3][w];
            const float pii = Pim[0][w] + Pim[1][w] + Pim[2][w] + Pim[3][w];
            const int idx = (v * w) & 255;
            const float c = twc[idx], s = tws[idx];
            ar += prr * c + pii * s;
            ai += pii * c - prr * s;
        }
        red_re[v][j] = ar; red_im[v][j] = ai;
    }
    __syncthreads();
    if (t < 16) {
        float ar = 0.f, ai = 0.f;
        #pragma unroll
        for (int j = 0; j < 16; ++j) { ar += red_re[t][j]; ai += red_im[t][j]; }
        float* sp = s_part + (size_t)bi * 128 + chunk * 32;
        sp[t]      = ar * (1.0f / 256.0f);
        sp[t + 16] = ai * (1.0f / 256.0f);
    }
}

// ---------------- K2: per-(b,o) blk + G-row coefficients -> global ----------------
// grid = 512 (b*32+o). coef layout: [bo][y][32]: [0..15]=cos-co, [16..31]=sin-co.
__global__ __launch_bounds__(256) void k2_coef(
    const float* __restrict__ wr, const float* __restrict__ wi,
    const float* __restrict__ s_part, float* __restrict__ coef)
{
    __shared__ float twc[256], tws[256];
    __shared__ float Sre[32][16], Sim[32][16];
    __shared__ float Br[256], Bi[256];

    const int t = threadIdx.x;
    const int bo = blockIdx.x;
    const int b = bo >> 5, o = bo & 31;

    {
        float sv, cv;
        sincosf(TWO_PI_OVER_256 * (float)t, &sv, &cv);
        twc[t] = cv; tws[t] = sv;
    }
    // Sum the 4 S partials: 512 (i,u) pairs / 256 threads = 2 each.
    {
        const float* sb = s_part + (size_t)b * 4096;
        #pragma unroll
        for (int e = t; e < 512; e += 256) {
            const int i = e >> 4, u = e & 15;
            const float* p = sb + i * 128 + u;
            Sre[i][u] = p[0] + p[32] + p[64] + p[96];
            Sim[i][u] = p[16] + p[48] + p[80] + p[112];
        }
    }
    __syncthreads();

    // blk[u,v] = sum_i S[b,i,u] * W[i,o,u,v] (complex); t == u*16+v
    {
        const int u = t >> 4;
        float br = 0.f, bim = 0.f;
        const float* wrp = wr + o * 256 + t;   // [i][o][u][v]
        const float* wip = wi + o * 256 + t;
        #pragma unroll 8
        for (int i = 0; i < 32; ++i) {
            const float a_re = Sre[i][u], a_im = Sim[i][u];
            const float w_re = wrp[i * 8192], w_im = wip[i * 8192];
            br  += a_re * w_re - a_im * w_im;
            bim += a_re * w_im + a_im * w_re;
        }
        Br[t] = br; Bi[t] = bim;
    }
    __syncthreads();

    // G rows: thread (v = t&15, yg = t>>4) handles 16 rows y = yg*16+m.
    {
        const int v = t & 15, yg = t >> 4;
        float br[16], bim[16];
        #pragma unroll
        for (int u = 0; u < 16; ++u) { br[u] = Br[u * 16 + v]; bim[u] = Bi[u * 16 + v]; }
        const float scale = (v == 0) ? (1.0f / 256.0f) : (1.0f / 128.0f);
        for (int m = 0; m < 16; ++m) {
            const int y = yg * 16 + m;
            const float c1 = twc[y], s1 = tws[y];   // e^{+2pi i y/256}
            float gr = br[0], gi = bim[0];
            float cc = 1.f, cs = 0.f;
            #pragma unroll
            for (int u = 1; u < 16; ++u) {
                const float nc = cc * c1 - cs * s1;
                const float ns = cc * s1 + cs * c1;
                cc = nc; cs = ns;
                gr += br[u] * cc - bim[u] * cs;
                gi += br[u] * cs + bim[u] * cc;
            }
            float* cp = coef + (((size_t)bo * 256 + y) << 5);
            cp[v]      = gr * scale;
            cp[16 + v] = (v == 0) ? 0.f : (-gi * scale);
        }
    }
}

// ---------------- K3: synthesis out[b,o,y,x], coef via wave-uniform s_load ----------------
// grid = 2048: bo x 4 row-chunks of 64.
__global__ __launch_bounds__(256) void k3_synth(
    const float* __restrict__ coef, float* __restrict__ out)
{
    __shared__ float twc[256], tws[256];
    const int t = threadIdx.x;
    const int blk = blockIdx.x;
    const int bo = blk >> 2;
    const int y0 = (blk & 3) << 6;

    {
        float sv, cv;
        sincosf(TWO_PI_OVER_256 * (float)t, &sv, &cv);
        twc[t] = cv; tws[t] = sv;
    }
    __syncthreads();

    float c[16], s[16];
    #pragma unroll
    for (int v = 0; v < 16; ++v) {
        const int idx = (v * t) & 255;
        c[v] = twc[idx];
        s[v] = tws[idx];
    }
    s[0] = 0.f;

    // cp is wave-uniform; all coef loads have uniform addresses -> SMEM s_load.
    const float* cp = coef + ((size_t)bo * 256 + y0) * 32;
    float* op = out + (size_t)bo * 65536 + (size_t)y0 * 256 + t;
    for (int r = 0; r < 64; ++r) {
        const float* p = cp + r * 32;
        float acc = 0.f;
        #pragma unroll
        for (int v = 0; v < 16; ++v) {
            acc += p[v] * c[v];
            acc += p[v + 16] * s[v];
        }
        op[r * 256] = acc;
    }
}

extern "C" void kernel_launch(void* const* d_in, const int* in_sizes, int n_in,
                              void* d_out, int out_size, void* d_ws, size_t ws_size,
                              hipStream_t stream) {
    (void)in_sizes; (void)n_in; (void)out_size; (void)ws_size;
    const float* x  = (const float*)d_in[0];
    const float* wr = (const float*)d_in[1];
    const float* wi = (const float*)d_in[2];
    float* out    = (float*)d_out;
    float* s_part = (float*)d_ws;          // 512 * 128 floats = 256 KB
    float* coef   = s_part + 65536;        // 512 * 256 * 32 floats = 16 MB

    k1_partial<<<2048, 256, 0, stream>>>(x, s_part);
    k2_coef<<<512, 256, 0, stream>>>(wr, wi, s_part, coef);
    k3_synth<<<2048, 256, 0, stream>>>(coef, out);
}